// Round 5
// baseline (427.835 us; speedup 1.0000x reference)
//
#include <hip/hip_runtime.h>
#include <hip/hip_cooperative_groups.h>
namespace cg = cooperative_groups;

#define SEQ 2048
#define DM  2048
// B = 2. Reference einsum 'bhql,bmhn->bhqn' does NOT contract l with m:
// out[b,q,:] = ((sum_s x[b,s,:]) @ wv^T) @ wo^T, broadcast over q.
// R4 post-mortem: 5-kernel chain = ~17us memory work + ~25us dispatch overhead.
// Fix: single cooperative kernel, grid.sync() between phases.

typedef float f4 __attribute__((ext_vector_type(4)));

__global__ __launch_bounds__(256, 4)
void fused_attn(const float* __restrict__ x, const float* __restrict__ wv,
                const float* __restrict__ wo, float* __restrict__ out,
                float* __restrict__ P, float* __restrict__ xsum,
                float* __restrict__ sv, float* __restrict__ rr) {
    cg::grid_group grid = cg::this_grid();
    const int bid  = blockIdx.x;       // 0..1023
    const int tid  = threadIdx.x;      // 0..255
    const int wid  = tid >> 6;         // wave 0..3
    const int lane = tid & 63;

    __shared__ float redB[4][64];
    __shared__ float pa[4], pb[4];

    // ---- Phase A: colsum partials. P[b][rc][:] = sum of 8 rows of x ----
    // bid -> (b, row-chunk rc of 8 rows, column half)
    {
        int b = bid >> 9, rem = bid & 511, rc = rem >> 1, half = rem & 1;
        int c4 = half * 256 + tid;                       // f4 column 0..511
        const f4* p = (const f4*)(x + ((size_t)b * SEQ + rc * 8) * DM) + c4;
        f4 acc = {0.f, 0.f, 0.f, 0.f};
#pragma unroll
        for (int r = 0; r < 8; ++r) acc += p[r * (DM / 4)];
        ((f4*)P)[(b * 256 + rc) * (DM / 4) + c4] = acc;
    }
    grid.sync();

    // ---- Phase B: xsum[b][c] = sum_k P[b][k][c]  (64 active blocks) ----
    if (bid < 64) {
        int b = bid >> 5, c = (bid & 31) * 64 + lane;    // wid = k-quarter
        const float* p = P + (size_t)(b * 256 + wid * 64) * DM + c;
        float a = 0.f;
#pragma unroll 8
        for (int k = 0; k < 64; ++k) a += p[(size_t)k * DM];
        redB[wid][lane] = a;
        __syncthreads();
        if (tid < 64)
            xsum[b * DM + (bid & 31) * 64 + tid] =
                redB[0][tid] + redB[1][tid] + redB[2][tid] + redB[3][tid];
    }
    grid.sync();

    // ---- Phase C: sv[b][n] = dot(xsum[b], wv[n]); n = bid*2 + (wid>>1) ----
    {
        int n = bid * 2 + (wid >> 1);
        int h = wid & 1;                                 // K-half per wave
        const f4* wr = (const f4*)(wv + (size_t)n * DM) + h * 256;
        const f4* x0 = (const f4*)xsum + h * 256;
        const f4* x1 = (const f4*)(xsum + DM) + h * 256;
        float a0 = 0.f, a1 = 0.f;
#pragma unroll
        for (int j = 0; j < 4; ++j) {
            f4 w = wr[lane + j * 64];
            f4 p = x0[lane + j * 64];
            f4 q = x1[lane + j * 64];
            a0 += w.x * p.x + w.y * p.y + w.z * p.z + w.w * p.w;
            a1 += w.x * q.x + w.y * q.y + w.z * q.z + w.w * q.w;
        }
#pragma unroll
        for (int m = 32; m; m >>= 1) { a0 += __shfl_xor(a0, m, 64); a1 += __shfl_xor(a1, m, 64); }
        if (lane == 0) { pa[wid] = a0; pb[wid] = a1; }
        __syncthreads();
        if (tid == 0)   { sv[n] = pa[0] + pa[1]; sv[DM + n] = pb[0] + pb[1]; }
        if (tid == 128) { sv[n] = pa[2] + pa[3]; sv[DM + n] = pb[2] + pb[3]; }
    }
    grid.sync();

    // ---- Phase D: rr[b][n] = dot(sv[b], wo[n]) ----
    {
        int n = bid * 2 + (wid >> 1);
        int h = wid & 1;
        const f4* wr = (const f4*)(wo + (size_t)n * DM) + h * 256;
        const f4* x0 = (const f4*)sv + h * 256;
        const f4* x1 = (const f4*)(sv + DM) + h * 256;
        float a0 = 0.f, a1 = 0.f;
#pragma unroll
        for (int j = 0; j < 4; ++j) {
            f4 w = wr[lane + j * 64];
            f4 p = x0[lane + j * 64];
            f4 q = x1[lane + j * 64];
            a0 += w.x * p.x + w.y * p.y + w.z * p.z + w.w * p.w;
            a1 += w.x * q.x + w.y * q.y + w.z * q.z + w.w * q.w;
        }
#pragma unroll
        for (int m = 32; m; m >>= 1) { a0 += __shfl_xor(a0, m, 64); a1 += __shfl_xor(a1, m, 64); }
        if (lane == 0) { pa[wid] = a0; pb[wid] = a1; }
        __syncthreads();
        if (tid == 0)   { rr[n] = pa[0] + pa[1]; rr[DM + n] = pb[0] + pb[1]; }
        if (tid == 128) { rr[n] = pa[2] + pa[3]; rr[DM + n] = pb[2] + pb[3]; }
    }
    grid.sync();

    // ---- Phase E: broadcast rr[b][:] to all q rows of out ----
    {
        const f4* r4 = (const f4*)rr;
#pragma unroll
        for (int j = 0; j < 8; ++j) {
            int idx = bid * 2048 + j * 256 + tid;        // f4 index, 2M total
            int b = idx >> 20;                           // SEQ*DM/4 = 2^20 per batch
            ((f4*)out)[idx] = r4[b * 512 + (idx & 511)];
        }
    }
}

extern "C" void kernel_launch(void* const* d_in, const int* in_sizes, int n_in,
                              void* d_out, int out_size, void* d_ws, size_t ws_size,
                              hipStream_t stream) {
    const float* x  = (const float*)d_in[0];
    const float* wv = (const float*)d_in[3];
    const float* wo = (const float*)d_in[4];
    float* out = (float*)d_out;

    float* ws   = (float*)d_ws;
    float* P    = ws;                 // 2*256*2048 floats = 4 MB
    float* xsum = P + 2 * 256 * DM;   // 2*2048
    float* sv   = xsum + 2 * DM;      // 2*2048
    float* rr   = sv + 2 * DM;        // 2*2048

    void* args[] = { (void*)&x, (void*)&wv, (void*)&wo, (void*)&out,
                     (void*)&P, (void*)&xsum, (void*)&sv, (void*)&rr };
    hipLaunchCooperativeKernel((void*)fused_attn, dim3(1024), dim3(256),
                               args, 0, stream);
}

// Round 6
// 39.035 us; speedup vs baseline: 10.9602x; 10.9602x over previous
//
#include <hip/hip_runtime.h>

#define SEQ 2048
#define DM  2048
// B = 2. Reference einsum 'bhql,bmhn->bhqn' does NOT contract l with m:
// out[b,q,:] = ((sum_s x[b,s,:]) @ wv^T) @ wo^T, broadcast over q.
// R5 post-mortem: cooperative grid.sync = ~100us/sync on MI355X (cross-XCD L2
// writeback per barrier). Kernel boundaries are the cheap flush mechanism.
// Structure: 4 kernels / 3 boundaries, no atomics, deterministic.

typedef float f4 __attribute__((ext_vector_type(4)));

// ---- K1: partial column sums (R1-proven): P[b*16+y][c] = sum of 128 rows ----
__global__ __launch_bounds__(256)
void colsum_part(const float* __restrict__ x, float* __restrict__ P) {
    int c = blockIdx.x * 256 + threadIdx.x;   // 0..2047
    int y = blockIdx.y;                       // 0..15
    int b = blockIdx.z;                       // 0..1
    const float* p = x + ((size_t)b * SEQ + (size_t)y * 128) * DM + c;
    float acc = 0.f;
#pragma unroll 8
    for (int r = 0; r < 128; ++r) acc += p[(size_t)r * DM];
    P[(size_t)(b * 16 + y) * DM + c] = acc;
}

// ---- K2: fused finish-colsum + matvec sv[b][n] = dot(xsum[b], wv[n]) ----
// Each block reduces its batch's 16 partials into LDS (L2-resident reads),
// then 4 waves compute 4 output rows from LDS + one global weight row each.
__global__ __launch_bounds__(256)
void redmatvec(const float* __restrict__ P, const float* __restrict__ W,
               float* __restrict__ o) {
    int b = blockIdx.y;
    __shared__ float xs[DM];
    const float* Pb = P + (size_t)b * 16 * DM;
    for (int cc = threadIdx.x; cc < DM; cc += 256) {
        float a = 0.f;
#pragma unroll
        for (int k = 0; k < 16; ++k) a += Pb[(size_t)k * DM + cc];
        xs[cc] = a;
    }
    __syncthreads();
    int w = threadIdx.x >> 6, lane = threadIdx.x & 63;
    int n = blockIdx.x * 4 + w;               // output row
    const f4* wr = (const f4*)(W + (size_t)n * DM);
    const f4* xv = (const f4*)xs;
    float a0 = 0.f;
#pragma unroll
    for (int i = lane; i < DM / 4; i += 64) {
        f4 a = wr[i];
        f4 p = xv[i];
        a0 += a.x * p.x + a.y * p.y + a.z * p.z + a.w * p.w;
    }
#pragma unroll
    for (int m = 32; m; m >>= 1) a0 += __shfl_xor(a0, m, 64);
    if (lane == 0) o[b * DM + n] = a0;
}

// ---- K3: matvec rr[b][n] = dot(sv[b], wo[n])  (R1-proven) ----
__global__ __launch_bounds__(256)
void matvec_nt(const float* __restrict__ v, const float* __restrict__ W,
               float* __restrict__ o) {
    int w    = threadIdx.x >> 6;
    int lane = threadIdx.x & 63;
    int n = blockIdx.x * 4 + w;
    int b = blockIdx.y;
    const f4* wr = (const f4*)(W + (size_t)n * DM);
    const f4* vr = (const f4*)(v + (size_t)b * DM);
    float acc = 0.f;
#pragma unroll
    for (int i = lane; i < DM / 4; i += 64) {
        f4 a = wr[i];
        f4 xx = vr[i];
        acc += a.x * xx.x + a.y * xx.y + a.z * xx.z + a.w * xx.w;
    }
#pragma unroll
    for (int m = 32; m; m >>= 1) acc += __shfl_xor(acc, m, 64);
    if (lane == 0) o[b * DM + n] = acc;
}

// ---- K4: broadcast rr[b][:] to all q rows (R1-proven) ----
__global__ __launch_bounds__(256)
void bcast_out(const float* __restrict__ r, float* __restrict__ out, int n4) {
    int i = blockIdx.x * 256 + threadIdx.x;
    if (i >= n4) return;
    int b  = (i >= (SEQ * DM / 4)) ? 1 : 0;
    int j4 = i & (DM / 4 - 1);
    ((f4*)out)[i] = ((const f4*)r)[b * (DM / 4) + j4];
}

extern "C" void kernel_launch(void* const* d_in, const int* in_sizes, int n_in,
                              void* d_out, int out_size, void* d_ws, size_t ws_size,
                              hipStream_t stream) {
    const float* x  = (const float*)d_in[0];
    const float* wv = (const float*)d_in[3];
    const float* wo = (const float*)d_in[4];
    float* out = (float*)d_out;

    float* ws = (float*)d_ws;
    float* P  = ws;                  // 32 * 2048 floats = 256 KB
    float* sv = P + 32 * DM;         // 2 * 2048
    float* rr = sv + 2 * DM;         // 2 * 2048

    colsum_part<<<dim3(8, 16, 2), 256, 0, stream>>>(x, P);
    redmatvec  <<<dim3(DM / 4, 2), 256, 0, stream>>>(P, wv, sv);
    matvec_nt  <<<dim3(DM / 4, 2), 256, 0, stream>>>(sv, wo, rr);

    int n4 = 2 * SEQ * DM / 4;       // 2,097,152 -> 8192 blocks
    bcast_out  <<<dim3(n4 / 256),  256, 0, stream>>>(rr, out, n4);
}

// Round 7
// 30.057 us; speedup vs baseline: 14.2339x; 1.2987x over previous
//
#include <hip/hip_runtime.h>

#define SEQ 2048
#define DM  2048
// B = 2. Reference einsum 'bhql,bmhn->bhqn' does NOT contract l with m:
// out[b,q,:] = ((sum_s x[b,s,:]) @ wv^T) @ wo^T, broadcast over q.
// R5: grid.sync ~100us each on MI355X -> never fuse across global deps.
// R6: redundant per-block re-reduction (134MB L3) cost +6us -> fuse only
//     when no redundant traffic. This round: fuse wo-matvec INTO the
//     broadcast kernel (each block owns 16 output columns; no duplication).

typedef float f4 __attribute__((ext_vector_type(4)));

// ---- K1 (R1-proven): partial column sums P[b*16+y][c] = sum of 128 rows ----
__global__ __launch_bounds__(256)
void colsum_part(const float* __restrict__ x, float* __restrict__ P) {
    int c = blockIdx.x * 256 + threadIdx.x;   // 0..2047
    int y = blockIdx.y;                       // 0..15
    int b = blockIdx.z;                       // 0..1
    const float* p = x + ((size_t)b * SEQ + (size_t)y * 128) * DM + c;
    float acc = 0.f;
#pragma unroll 8
    for (int r = 0; r < 128; ++r) acc += p[(size_t)r * DM];
    P[(size_t)(b * 16 + y) * DM + c] = acc;
}

// ---- K2 (R1-proven): xsum[b][c] = sum of 16 partials ----
__global__ __launch_bounds__(256)
void colsum_final(const float* __restrict__ P, float* __restrict__ xsum) {
    int c = blockIdx.x * 256 + threadIdx.x;
    int b = blockIdx.y;
    const float* p = P + (size_t)b * 16 * DM + c;
    float a = 0.f;
#pragma unroll
    for (int y = 0; y < 16; ++y) a += p[(size_t)y * DM];
    xsum[b * DM + c] = a;
}

// ---- K3 (R1-proven): sv[b][n] = dot(xsum[b], wv[n]) ----
__global__ __launch_bounds__(256)
void matvec_nt(const float* __restrict__ v, const float* __restrict__ W,
               float* __restrict__ o) {
    int w    = threadIdx.x >> 6;
    int lane = threadIdx.x & 63;
    int n = blockIdx.x * 4 + w;
    int b = blockIdx.y;
    const f4* wr = (const f4*)(W + (size_t)n * DM);
    const f4* vr = (const f4*)(v + (size_t)b * DM);
    float acc = 0.f;
#pragma unroll
    for (int i = lane; i < DM / 4; i += 64) {
        f4 a = wr[i];
        f4 xx = vr[i];
        acc += a.x * xx.x + a.y * xx.y + a.z * xx.z + a.w * xx.w;
    }
#pragma unroll
    for (int m = 32; m; m >>= 1) acc += __shfl_xor(acc, m, 64);
    if (lane == 0) o[b * DM + n] = acc;
}

// ---- K4 (new): fused wo-matvec + broadcast ----
// Block (nc, b) owns output columns n0..n0+15 of batch b.
// Phase 1: 8 waves compute the 16 dots rr[n0..n0+15] (wo rows read once per
//          batch; batch-dup read hits shared L3). Phase 2: write those 16
//          columns for all 2048 q rows (64-B line segments per row).
__global__ __launch_bounds__(512)
void matvec_bcast(const float* __restrict__ v, const float* __restrict__ W,
                  float* __restrict__ out) {
    int b  = blockIdx.y;
    int n0 = blockIdx.x * 16;
    __shared__ __align__(16) float rloc[16];
    int w = threadIdx.x >> 6, lane = threadIdx.x & 63;
    const f4* vr = (const f4*)(v + (size_t)b * DM);
#pragma unroll
    for (int r = 0; r < 2; ++r) {             // wave w -> rows n0+2w, n0+2w+1
        int n = n0 + w * 2 + r;
        const f4* wr = (const f4*)(W + (size_t)n * DM);
        float a = 0.f;
#pragma unroll
        for (int i = lane; i < DM / 4; i += 64) {
            f4 aa = wr[i];
            f4 p  = vr[i];
            a += aa.x * p.x + aa.y * p.y + aa.z * p.z + aa.w * p.w;
        }
#pragma unroll
        for (int m = 32; m; m >>= 1) a += __shfl_xor(a, m, 64);
        if (lane == 0) rloc[w * 2 + r] = a;
    }
    __syncthreads();
    f4 val = ((const f4*)rloc)[threadIdx.x & 3];      // 4 threads share a row
    float* ob = out + (size_t)b * SEQ * DM + n0;
    int qb = threadIdx.x >> 2;                        // 0..127
#pragma unroll
    for (int it = 0; it < 16; ++it) {
        int q = qb + it * 128;                        // covers 0..2047
        ((f4*)(ob + (size_t)q * DM))[threadIdx.x & 3] = val;
    }
}

extern "C" void kernel_launch(void* const* d_in, const int* in_sizes, int n_in,
                              void* d_out, int out_size, void* d_ws, size_t ws_size,
                              hipStream_t stream) {
    const float* x  = (const float*)d_in[0];
    const float* wv = (const float*)d_in[3];
    const float* wo = (const float*)d_in[4];
    float* out = (float*)d_out;

    float* ws   = (float*)d_ws;
    float* P    = ws;                 // 32 * 2048 floats
    float* xsum = P + 32 * DM;        // 2 * 2048
    float* sv   = xsum + 2 * DM;      // 2 * 2048

    colsum_part <<<dim3(8, 16, 2),  256, 0, stream>>>(x, P);
    colsum_final<<<dim3(8, 2),      256, 0, stream>>>(P, xsum);
    matvec_nt   <<<dim3(DM / 4, 2), 256, 0, stream>>>(xsum, wv, sv);
    matvec_bcast<<<dim3(DM / 16, 2), 512, 0, stream>>>(sv, wo, out);
}